// Round 5
// baseline (243.603 us; speedup 1.0000x reference)
//
#include <hip/hip_runtime.h>

typedef __attribute__((ext_vector_type(8))) short short8;
typedef __attribute__((ext_vector_type(4))) float floatx4;

__device__ __forceinline__ unsigned short f2bf(float f) {
    union { float f; unsigned int u; } v; v.f = f;
    unsigned int r = (v.u + 0x7fffu + ((v.u >> 16) & 1u)) >> 16;
    return (unsigned short)r;
}

// ---------------------------------------------------------------------------
// T: ctrl [8,128,128,128] f32 NCHW -> ctrlT [8,128y,128x,128ci] bf16 NHWC
// ---------------------------------------------------------------------------
__global__ __launch_bounds__(256) void transpose_kernel(
    const float* __restrict__ ctrl, unsigned short* __restrict__ ctrlT)
{
    __shared__ unsigned short tile[64 * 66];
    const int t = threadIdx.x;
    const int x0 = blockIdx.x * 64, ci0 = blockIdx.y * 64;
    const int b = blockIdx.z >> 7, y = blockIdx.z & 127;
#pragma unroll
    for (int it = 0; it < 4; it++) {
        int ci_l = it * 16 + (t >> 4);
        int x_l = (t & 15) * 4;
        const float4 v = *(const float4*)&ctrl[(((size_t)b * 128 + ci0 + ci_l) * 128 + y) * 128 + x0 + x_l];
        tile[(x_l + 0) * 66 + ci_l] = f2bf(v.x);
        tile[(x_l + 1) * 66 + ci_l] = f2bf(v.y);
        tile[(x_l + 2) * 66 + ci_l] = f2bf(v.z);
        tile[(x_l + 3) * 66 + ci_l] = f2bf(v.w);
    }
    __syncthreads();
#pragma unroll
    for (int it = 0; it < 2; it++) {
        int x_l = it * 32 + (t >> 3);
        int ci_l = (t & 7) * 8;
        const unsigned int* p = (const unsigned int*)&tile[x_l * 66 + ci_l];
        uint4 u = make_uint4(p[0], p[1], p[2], p[3]);
        *(uint4*)&ctrlT[(((size_t)b * 128 + y) * 128 + x0 + x_l) * 128 + ci0 + ci_l] = u;
    }
}

// ---------------------------------------------------------------------------
// W-prep: w1 -> [c4=4][tap=9][co=64][ci=32] bf16 ; w2 -> [c4=2][tap=9][co=32][ci=32]
// ---------------------------------------------------------------------------
__global__ __launch_bounds__(256) void prep_w_kernel(
    const float* __restrict__ w1, const float* __restrict__ w2,
    unsigned short* __restrict__ w1p, unsigned short* __restrict__ w2p)
{
    int i = blockIdx.x * 256 + threadIdx.x;
    if (i < 4 * 9 * 64 * 32) {
        int ci = i & 31; int t2 = i >> 5; int co = t2 & 63; int t3 = t2 >> 6;
        int tap = t3 % 9; int c4 = t3 / 9;
        float v = 0.f;
        if (co < 50) v = w1[((size_t)co * 128 + c4 * 32 + ci) * 9 + tap];
        w1p[i] = f2bf(v);
    } else {
        int j = i - 4 * 9 * 64 * 32;
        int ci = j & 31; int t2 = j >> 5; int co = t2 & 31; int t3 = t2 >> 5;
        int tap = t3 % 9; int c4 = t3 / 9;
        int cig = c4 * 32 + ci;
        float v = 0.f;
        if (co < 18 && cig < 50) v = w2[((size_t)co * 50 + cig) * 9 + tap];
        w2p[j] = f2bf(v);
    }
}

// ---------------------------------------------------------------------------
// conv1 MFMA v4: R2 core (LDS staging for input + weights) with T14 reg-
// prefetch: c4+1 global loads issued BEFORE compute c4, LDS writes AFTER the
// post-compute barrier. Weights stay in LDS (R3 lesson). LDS 72 KB, 2 bl/CU.
// ---------------------------------------------------------------------------
__global__ __launch_bounds__(256) void conv1_mfma(
    const unsigned short* __restrict__ xT, const unsigned short* __restrict__ w1p,
    const float* __restrict__ b1, const float* __restrict__ gamma,
    const float* __restrict__ beta, const float* __restrict__ mean,
    const float* __restrict__ var, unsigned short* __restrict__ h)
{
    __shared__ unsigned short in_s[324 * 40];     // 18x18 px halo, 32 ci (pad 40)
    __shared__ unsigned short w_s[9 * 64 * 40];   // tap x co x 32 ci
    const int tid = threadIdx.x;
    const int x0 = blockIdx.x * 16, y0 = blockIdx.y * 16, b = blockIdx.z;
    const int wid = tid >> 6, lane = tid & 63;
    const int ln = lane & 15, q = lane >> 4;

    floatx4 acc[4][4];
#pragma unroll
    for (int mt = 0; mt < 4; mt++)
#pragma unroll
        for (int nt = 0; nt < 4; nt++) acc[mt][nt] = (floatx4)(0.f);

    uint4 in_r[6], w_r[9];
    auto load_in = [&](int c4) {
#pragma unroll
        for (int k = 0; k < 6; k++) {
            int i = tid + k * 256;
            if (i < 1296) {
                int p = i >> 2, g = i & 3;
                int gy = y0 + p / 18 - 1, gx = x0 + p % 18 - 1;
                in_r[k] = make_uint4(0, 0, 0, 0);
                if (gy >= 0 && gy < 128 && gx >= 0 && gx < 128)
                    in_r[k] = *(const uint4*)&xT[(((size_t)b * 128 + gy) * 128 + gx) * 128 + c4 * 32 + g * 8];
            }
        }
    };
    auto load_w = [&](int c4) {
#pragma unroll
        for (int it = 0; it < 9; it++) {
            int f = it * 256 + tid;
            int g = f & 3, co = (f >> 2) & 63, tap = f >> 8;
            w_r[it] = *(const uint4*)&w1p[(((size_t)c4 * 9 + tap) * 64 + co) * 32 + g * 8];
        }
    };
    auto write_in = [&]() {
#pragma unroll
        for (int k = 0; k < 6; k++) {
            int i = tid + k * 256;
            if (i < 1296) {
                int p = i >> 2, g = i & 3;
                *(uint4*)&in_s[p * 40 + g * 8] = in_r[k];
            }
        }
    };
    auto write_w = [&]() {
#pragma unroll
        for (int it = 0; it < 9; it++) {
            int f = it * 256 + tid;
            int g = f & 3, co = (f >> 2) & 63, tap = f >> 8;
            *(uint4*)&w_s[(tap * 64 + co) * 40 + g * 8] = w_r[it];
        }
    };

    load_in(0); load_w(0);
    write_in(); write_w();
    __syncthreads();

    for (int c4 = 0; c4 < 4; c4++) {
        if (c4 < 3) { load_in(c4 + 1); load_w(c4 + 1); }   // issue early; hides under MFMA
#pragma unroll
        for (int tap = 0; tap < 9; tap++) {
            const int dy = tap / 3, dx = tap % 3;
            short8 a[4];
#pragma unroll
            for (int mt = 0; mt < 4; mt++)
                a[mt] = *(const short8*)&in_s[((wid * 4 + mt + dy) * 18 + ln + dx) * 40 + q * 8];
#pragma unroll
            for (int nt = 0; nt < 4; nt++) {
                short8 bf = *(const short8*)&w_s[(tap * 64 + nt * 16 + ln) * 40 + q * 8];
#pragma unroll
                for (int mt = 0; mt < 4; mt++)
                    acc[mt][nt] = __builtin_amdgcn_mfma_f32_16x16x32_bf16(a[mt], bf, acc[mt][nt], 0, 0, 0);
            }
        }
        __syncthreads();                                    // all waves done reading LDS
        if (c4 < 3) { write_in(); write_w(); __syncthreads(); }
    }

#pragma unroll
    for (int nt = 0; nt < 4; nt++) {
        int co = nt * 16 + ln;
        bool real = co < 50;
        float sc = 0.f, mn = 0.f, bt = 0.f, bs = 0.f;
        if (real) {
            sc = gamma[co] * rsqrtf(var[co] + 1e-5f);
            mn = mean[co]; bt = beta[co]; bs = b1[co];
        }
#pragma unroll
        for (int mt = 0; mt < 4; mt++) {
            int gy = y0 + wid * 4 + mt;
#pragma unroll
            for (int r = 0; r < 4; r++) {
                int px = q * 4 + r;
                float v = 0.f;
                if (real) {
                    float tv = fmaxf(acc[mt][nt][r] + bs, 0.f);
                    v = (tv - mn) * sc + bt;
                }
                h[(((size_t)b * 128 + gy) * 128 + x0 + px) * 64 + co] = f2bf(v);
            }
        }
    }
}

// ---------------------------------------------------------------------------
// conv2 MFMA v4: ALL weights staged once (46 KB, both c4); input reg-prefetch.
// Epilogue writes cond split by channel-group:
//   cond[b][g][cy][cx][12], slot = jy*4 + iw  (iw = i = width tap)
// ---------------------------------------------------------------------------
__global__ __launch_bounds__(256) void conv2_mfma(
    const unsigned short* __restrict__ hT, const unsigned short* __restrict__ w2p,
    const float* __restrict__ b2, float* __restrict__ cond)
{
    __shared__ unsigned short in_s[324 * 40];
    __shared__ unsigned short w_s[2][9 * 32 * 40];
    const int tid = threadIdx.x;
    const int x0 = blockIdx.x * 16, y0 = blockIdx.y * 16, b = blockIdx.z;
    const int wid = tid >> 6, lane = tid & 63;
    const int ln = lane & 15, q = lane >> 4;

    floatx4 acc[4][2];
#pragma unroll
    for (int mt = 0; mt < 4; mt++)
#pragma unroll
        for (int nt = 0; nt < 2; nt++) acc[mt][nt] = (floatx4)(0.f);

    uint4 in_r[6];
    auto load_in = [&](int c4) {
#pragma unroll
        for (int k = 0; k < 6; k++) {
            int i = tid + k * 256;
            if (i < 1296) {
                int p = i >> 2, g = i & 3;
                int gy = y0 + p / 18 - 1, gx = x0 + p % 18 - 1;
                in_r[k] = make_uint4(0, 0, 0, 0);
                if (gy >= 0 && gy < 128 && gx >= 0 && gx < 128)
                    in_r[k] = *(const uint4*)&hT[(((size_t)b * 128 + gy) * 128 + gx) * 64 + c4 * 32 + g * 8];
            }
        }
    };
    auto write_in = [&]() {
#pragma unroll
        for (int k = 0; k < 6; k++) {
            int i = tid + k * 256;
            if (i < 1296) {
                int p = i >> 2, g = i & 3;
                *(uint4*)&in_s[p * 40 + g * 8] = in_r[k];
            }
        }
    };

    // stage ALL weights (2 c4 x 1152 uint4 = 2304), 9 per thread
    load_in(0);
#pragma unroll
    for (int it = 0; it < 9; it++) {
        int f = it * 256 + tid;
        int c4w = f >= 1152 ? 1 : 0;
        int f2 = f - c4w * 1152;
        int g = f2 & 3, co = (f2 >> 2) & 31, tap = f2 >> 7;
        uint4 v = *(const uint4*)&w2p[(((size_t)c4w * 9 + tap) * 32 + co) * 32 + g * 8];
        *(uint4*)&w_s[c4w][(tap * 32 + co) * 40 + g * 8] = v;
    }
    write_in();
    __syncthreads();

    for (int c4 = 0; c4 < 2; c4++) {
        if (c4 < 1) load_in(1);
#pragma unroll
        for (int tap = 0; tap < 9; tap++) {
            const int dy = tap / 3, dx = tap % 3;
            short8 a[4];
#pragma unroll
            for (int mt = 0; mt < 4; mt++)
                a[mt] = *(const short8*)&in_s[((wid * 4 + mt + dy) * 18 + ln + dx) * 40 + q * 8];
#pragma unroll
            for (int nt = 0; nt < 2; nt++) {
                short8 bf = *(const short8*)&w_s[c4][(tap * 32 + nt * 16 + ln) * 40 + q * 8];
#pragma unroll
                for (int mt = 0; mt < 4; mt++)
                    acc[mt][nt] = __builtin_amdgcn_mfma_f32_16x16x32_bf16(a[mt], bf, acc[mt][nt], 0, 0, 0);
            }
        }
        if (c4 < 1) {
            __syncthreads();
            write_in();
            __syncthreads();
        }
    }

#pragma unroll
    for (int nt = 0; nt < 2; nt++) {
        int co = nt * 16 + ln;
        if (co < 18) {
            float bs = b2[co];
            int gch = co / 9, k = co % 9;
            int iw = k / 3, jy = k % 3;
#pragma unroll
            for (int mt = 0; mt < 4; mt++) {
                int gy = y0 + wid * 4 + mt;
#pragma unroll
                for (int r = 0; r < 4; r++) {
                    int px = q * 4 + r;
                    cond[((((size_t)b * 2 + gch) * 128 + gy) * 128 + (x0 + px)) * 12 + jy * 4 + iw]
                        = acc[mt][nt][r] + bs;
                }
            }
        }
    }
}

// ---------------------------------------------------------------------------
// apply v4: direct per-output-row gather with ALIGNED +/-4px tap loads.
// Taps are +/-4 px = exactly one float4 left/right -> 3 aligned float4 loads
// per (jy,cc), no shuffles, no LDS. cond: one float4 per jy ([b][g][cy][cx][12]).
// Flat grid 4096 with XCD-chunked decode: each XCD gets contiguous by-ranges
// of 2 bz-slices -> row re-reads stay in one XCD's L2.
// ---------------------------------------------------------------------------
__global__ __launch_bounds__(256) void apply_kernel(
    const float* __restrict__ img, const float* __restrict__ cond,
    float* __restrict__ out)
{
    // XCD-chunked bijective swizzle: 4096 blocks, 8 XCDs, 512 per chunk.
    const int hwid = blockIdx.x;
    const int lid = (hwid & 7) * 512 + (hwid >> 3);
    const int bx = lid & 1, by = (lid >> 1) & 127, bz = lid >> 8;

    const int tid = threadIdx.x;
    const int xl = tid & 63, s = tid >> 6;
    const int x4 = bx * 64 + xl;
    const int o = by * 4 + s;                 // output row (wave-uniform)
    const int b = bz >> 1, g = bz & 1;
    const int xo = x4 * 4;

    // weights: 3 aligned float4 (jy = 0,1,2); .x=i0(x-4) .y=i1(x) .z=i2(x+4)
    const float* cw = &cond[((((size_t)b * 2 + g) * 128 + by) * 128 + x4) * 12];
    float4 w0 = *(const float4*)&cw[0];
    float4 w1 = *(const float4*)&cw[4];
    float4 w2 = *(const float4*)&cw[8];

    // all img loads issued up front, fully independent
    float4 C[3][3], L[3][3], R[3][3];
    const bool lok = (x4 > 0), rok_x = (x4 < 127);
#pragma unroll
    for (int jy = 0; jy < 3; jy++) {
        const int r = o - 4 + 4 * jy;
        const bool rk = (r >= 0) && (r < 512); // wave-uniform
#pragma unroll
        for (int cc = 0; cc < 3; cc++) {
            C[jy][cc] = make_float4(0.f, 0.f, 0.f, 0.f);
            L[jy][cc] = make_float4(0.f, 0.f, 0.f, 0.f);
            R[jy][cc] = make_float4(0.f, 0.f, 0.f, 0.f);
            if (rk) {
                const float* rp = &img[((((size_t)b * 6 + g * 3 + cc) * 512) + r) * 512];
                C[jy][cc] = *(const float4*)&rp[xo];
                if (lok)   L[jy][cc] = *(const float4*)&rp[xo - 4];
                if (rok_x) R[jy][cc] = *(const float4*)&rp[xo + 4];
            }
        }
    }

    float4 acc[3];
#pragma unroll
    for (int cc = 0; cc < 3; cc++) acc[cc] = make_float4(0.f, 0.f, 0.f, 0.f);

#pragma unroll
    for (int jy = 0; jy < 3; jy++) {
        const float4 wj = (jy == 0) ? w0 : (jy == 1) ? w1 : w2;
#pragma unroll
        for (int cc = 0; cc < 3; cc++) {
            const float4 l = L[jy][cc], c = C[jy][cc], r = R[jy][cc];
            acc[cc].x += l.x * wj.x + c.x * wj.y + r.x * wj.z;
            acc[cc].y += l.y * wj.x + c.y * wj.y + r.y * wj.z;
            acc[cc].z += l.z * wj.x + c.z * wj.y + r.z * wj.z;
            acc[cc].w += l.w * wj.x + c.w * wj.y + r.w * wj.z;
        }
    }

#pragma unroll
    for (int cc = 0; cc < 3; cc++)
        *(float4*)&out[((((size_t)b * 6 + g * 3 + cc) * 512) + o) * 512 + xo] = acc[cc];
}

// ---------------------------------------------------------------------------
extern "C" void kernel_launch(void* const* d_in, const int* in_sizes, int n_in,
                              void* d_out, int out_size, void* d_ws, size_t ws_size,
                              hipStream_t stream)
{
    const float* img   = (const float*)d_in[0];
    const float* ctrl  = (const float*)d_in[1];
    const float* w1    = (const float*)d_in[2];
    const float* b1    = (const float*)d_in[3];
    const float* gamma = (const float*)d_in[4];
    const float* beta  = (const float*)d_in[5];
    const float* mean  = (const float*)d_in[6];
    const float* var   = (const float*)d_in[7];
    const float* w2    = (const float*)d_in[8];
    const float* b2    = (const float*)d_in[9];
    float* out = (float*)d_out;

    char* ws = (char*)d_ws;
    // cond reuses the ctrlT region: ctrlT is dead after conv1, cond is written
    // by conv2 (stream-ordered after conv1) and read only by apply.
    unsigned short* ctrlT = (unsigned short*)ws;                        // 33,554,432 B
    float*          cond  = (float*)ws;                                 // 12,582,912 B (overlap)
    unsigned short* hbuf  = (unsigned short*)(ws + 33554432);           // 16,777,216 B
    unsigned short* w1p   = (unsigned short*)(ws + 50331648);           //    147,456 B
    unsigned short* w2p   = (unsigned short*)(ws + 50479104);           //     36,864 B

    transpose_kernel<<<dim3(2, 2, 1024), 256, 0, stream>>>(ctrl, ctrlT);
    prep_w_kernel<<<360, 256, 0, stream>>>(w1, w2, w1p, w2p);
    conv1_mfma<<<dim3(8, 8, 8), 256, 0, stream>>>(ctrlT, w1p, b1, gamma, beta, mean, var, hbuf);
    conv2_mfma<<<dim3(8, 8, 8), 256, 0, stream>>>(hbuf, w2p, b2, cond);
    apply_kernel<<<4096, 256, 0, stream>>>(img, cond, out);
}

// Round 6
// 225.910 us; speedup vs baseline: 1.0783x; 1.0783x over previous
//
#include <hip/hip_runtime.h>

typedef __attribute__((ext_vector_type(8))) short short8;
typedef __attribute__((ext_vector_type(4))) float floatx4;

__device__ __forceinline__ unsigned short f2bf(float f) {
    union { float f; unsigned int u; } v; v.f = f;
    unsigned int r = (v.u + 0x7fffu + ((v.u >> 16) & 1u)) >> 16;
    return (unsigned short)r;
}

// async global -> LDS, 16B per lane. LDS dest = wave-uniform base + lane*16.
__device__ __forceinline__ void gload_lds16(const void* g, void* l) {
    __builtin_amdgcn_global_load_lds(
        (const __attribute__((address_space(1))) unsigned int*)g,
        (__attribute__((address_space(3))) unsigned int*)l, 16, 0, 0);
}

// ---------------------------------------------------------------------------
// T: ctrl [8,128,128,128] f32 NCHW -> ctrlT [8,130,130,128ci] bf16 NHWC+halo.
// Interior only; prep zeroes the 1-px border.
// ---------------------------------------------------------------------------
__global__ __launch_bounds__(256) void transpose_kernel(
    const float* __restrict__ ctrl, unsigned short* __restrict__ ctrlT)
{
    __shared__ unsigned short tile[64 * 66];
    const int t = threadIdx.x;
    const int x0 = blockIdx.x * 64, ci0 = blockIdx.y * 64;
    const int b = blockIdx.z >> 7, y = blockIdx.z & 127;
#pragma unroll
    for (int it = 0; it < 4; it++) {
        int ci_l = it * 16 + (t >> 4);
        int x_l = (t & 15) * 4;
        const float4 v = *(const float4*)&ctrl[(((size_t)b * 128 + ci0 + ci_l) * 128 + y) * 128 + x0 + x_l];
        tile[(x_l + 0) * 66 + ci_l] = f2bf(v.x);
        tile[(x_l + 1) * 66 + ci_l] = f2bf(v.y);
        tile[(x_l + 2) * 66 + ci_l] = f2bf(v.z);
        tile[(x_l + 3) * 66 + ci_l] = f2bf(v.w);
    }
    __syncthreads();
#pragma unroll
    for (int it = 0; it < 2; it++) {
        int x_l = it * 32 + (t >> 3);
        int ci_l = (t & 7) * 8;
        const unsigned int* p = (const unsigned int*)&tile[x_l * 66 + ci_l];
        uint4 u = make_uint4(p[0], p[1], p[2], p[3]);
        *(uint4*)&ctrlT[(((size_t)b * 130 + (y + 1)) * 130 + (x0 + x_l + 1)) * 128 + ci0 + ci_l] = u;
    }
}

// ---------------------------------------------------------------------------
// W-prep + halo zeroing.
//   w1 -> [c4=4][tap=9][co=64][ci=32] bf16 ; w2 -> [c4=2][tap=9][co=32][ci=32]
//   + zero ctrlT halo border (8 x 516 px x 16 uint4)
//   + zero hbuf  halo border (8 x 516 px x  8 uint4)
// grid 747 * 256 = 191,232 items exactly.
// ---------------------------------------------------------------------------
__global__ __launch_bounds__(256) void prep_w_kernel(
    const float* __restrict__ w1, const float* __restrict__ w2,
    unsigned short* __restrict__ w1p, unsigned short* __restrict__ w2p,
    unsigned short* __restrict__ ctrlT, unsigned short* __restrict__ hbuf)
{
    int i = blockIdx.x * 256 + threadIdx.x;
    if (i < 73728) {
        int ci = i & 31; int t2 = i >> 5; int co = t2 & 63; int t3 = t2 >> 6;
        int tap = t3 % 9; int c4 = t3 / 9;
        float v = 0.f;
        if (co < 50) v = w1[((size_t)co * 128 + c4 * 32 + ci) * 9 + tap];
        w1p[i] = f2bf(v);
    } else if (i < 92160) {
        int j = i - 73728;
        int ci = j & 31; int t2 = j >> 5; int co = t2 & 31; int t3 = t2 >> 5;
        int tap = t3 % 9; int c4 = t3 / 9;
        int cig = c4 * 32 + ci;
        float v = 0.f;
        if (co < 18 && cig < 50) v = w2[((size_t)co * 50 + cig) * 9 + tap];
        w2p[j] = f2bf(v);
    } else if (i < 158208) {
        int k = i - 92160;                       // ctrlT border
        int b = k / 8256, r = k % 8256;
        int px = r >> 4, u4 = r & 15;
        int Y, X;
        if (px < 130)      { Y = 0;        X = px; }
        else if (px < 260) { Y = 129;      X = px - 130; }
        else if (px < 388) { Y = px - 259; X = 0; }
        else               { Y = px - 387; X = 129; }
        *(uint4*)&ctrlT[(((size_t)b * 130 + Y) * 130 + X) * 128 + u4 * 8] = make_uint4(0, 0, 0, 0);
    } else {
        int k = i - 158208;                      // hbuf border
        int b = k / 4128, r = k % 4128;
        int px = r >> 3, u4 = r & 7;
        int Y, X;
        if (px < 130)      { Y = 0;        X = px; }
        else if (px < 260) { Y = 129;      X = px - 130; }
        else if (px < 388) { Y = px - 259; X = 0; }
        else               { Y = px - 387; X = 129; }
        *(uint4*)&hbuf[(((size_t)b * 130 + Y) * 130 + X) * 64 + u4 * 8] = make_uint4(0, 0, 0, 0);
    }
}

// ---------------------------------------------------------------------------
// conv1 MFMA v5 (m97-style): staging via global_load_lds width-16, linear
// pad-free LDS, zero bounds checks (halo'd ctrlT). 2-barrier/c4 structure.
// LDS 58.4 KB -> 2 blocks/CU. No staging VGPRs.
// ---------------------------------------------------------------------------
__global__ __launch_bounds__(256) void conv1_mfma(
    const unsigned short* __restrict__ xT, const unsigned short* __restrict__ w1p,
    const float* __restrict__ b1, const float* __restrict__ gamma,
    const float* __restrict__ beta, const float* __restrict__ mean,
    const float* __restrict__ var, unsigned short* __restrict__ h)
{
    __shared__ unsigned short in_s[1344 * 8];   // 324 px * 4 ci-slots (+ slack), linear
    __shared__ unsigned short w_s[2304 * 8];    // 9 taps * 64 co * 4 ci-slots, linear
    const int tid = threadIdx.x;
    const int x0 = blockIdx.x * 16, y0 = blockIdx.y * 16, b = blockIdx.z;
    const int wid = tid >> 6, lane = tid & 63;
    const int ln = lane & 15, q = lane >> 4;

    floatx4 acc[4][4];
#pragma unroll
    for (int mt = 0; mt < 4; mt++)
#pragma unroll
        for (int nt = 0; nt < 4; nt++) acc[mt][nt] = (floatx4)(0.f);

    for (int c4 = 0; c4 < 4; c4++) {
        // stage input: 1296 uint4 in 6 chunks (last chunk: wave 0 only, clamped)
#pragma unroll
        for (int it = 0; it < 6; it++) {
            const int cbase = it * 256 + wid * 64;
            if (cbase < 1296) {
                int j = cbase + lane; if (j > 1295) j = 1295;
                const int p = j >> 2, s = j & 3;
                const int Y = y0 + p / 18, X = x0 + p % 18;
                gload_lds16(&xT[(((size_t)b * 130 + Y) * 130 + X) * 128 + c4 * 32 + s * 8],
                            &in_s[(size_t)cbase * 8]);
            }
        }
        // stage weights: 2304 uint4, pure linear copy
        const unsigned short* wsrc = &w1p[(size_t)c4 * 2304 * 8];
#pragma unroll
        for (int it = 0; it < 9; it++) {
            const int cbase = it * 256 + wid * 64;
            gload_lds16(&wsrc[(size_t)(cbase + lane) * 8], &w_s[(size_t)cbase * 8]);
        }
        __syncthreads();   // compiler drains vmcnt(0) here -> LDS valid

#pragma unroll
        for (int tap = 0; tap < 9; tap++) {
            const int dy = tap / 3, dx = tap % 3;
            short8 a[4];
#pragma unroll
            for (int mt = 0; mt < 4; mt++)
                a[mt] = *(const short8*)&in_s[(((wid * 4 + mt + dy) * 18 + ln + dx) * 4 + q) * 8];
#pragma unroll
            for (int nt = 0; nt < 4; nt++) {
                short8 bf = *(const short8*)&w_s[((tap * 64 + nt * 16 + ln) * 4 + q) * 8];
#pragma unroll
                for (int mt = 0; mt < 4; mt++)
                    acc[mt][nt] = __builtin_amdgcn_mfma_f32_16x16x32_bf16(a[mt], bf, acc[mt][nt], 0, 0, 0);
            }
        }
        __syncthreads();
    }

#pragma unroll
    for (int nt = 0; nt < 4; nt++) {
        int co = nt * 16 + ln;
        bool real = co < 50;
        float sc = 0.f, mn = 0.f, bt = 0.f, bs = 0.f;
        if (real) {
            sc = gamma[co] * rsqrtf(var[co] + 1e-5f);
            mn = mean[co]; bt = beta[co]; bs = b1[co];
        }
#pragma unroll
        for (int mt = 0; mt < 4; mt++) {
            int gy = y0 + wid * 4 + mt;
#pragma unroll
            for (int r = 0; r < 4; r++) {
                int px = q * 4 + r;
                float v = 0.f;
                if (real) {
                    float tv = fmaxf(acc[mt][nt][r] + bs, 0.f);
                    v = (tv - mn) * sc + bt;
                }
                // halo'd hbuf: interior write at (gy+1, gx+1)
                h[(((size_t)b * 130 + (gy + 1)) * 130 + (x0 + px + 1)) * 64 + co] = f2bf(v);
            }
        }
    }
}

// ---------------------------------------------------------------------------
// conv2 MFMA v5: same m97-style staging from halo'd hbuf. LDS 39.9 KB ->
// 4 blocks/CU. Epilogue writes cond[b][g][cy][cx][12] (R5-verified layout).
// ---------------------------------------------------------------------------
__global__ __launch_bounds__(256) void conv2_mfma(
    const unsigned short* __restrict__ hT, const unsigned short* __restrict__ w2p,
    const float* __restrict__ b2, float* __restrict__ cond)
{
    __shared__ unsigned short in_s[1344 * 8];
    __shared__ unsigned short w_s[1152 * 8];    // 9 taps * 32 co * 4 ci-slots
    const int tid = threadIdx.x;
    const int x0 = blockIdx.x * 16, y0 = blockIdx.y * 16, b = blockIdx.z;
    const int wid = tid >> 6, lane = tid & 63;
    const int ln = lane & 15, q = lane >> 4;

    floatx4 acc[4][2];
#pragma unroll
    for (int mt = 0; mt < 4; mt++)
#pragma unroll
        for (int nt = 0; nt < 2; nt++) acc[mt][nt] = (floatx4)(0.f);

    for (int c4 = 0; c4 < 2; c4++) {
#pragma unroll
        for (int it = 0; it < 6; it++) {
            const int cbase = it * 256 + wid * 64;
            if (cbase < 1296) {
                int j = cbase + lane; if (j > 1295) j = 1295;
                const int p = j >> 2, s = j & 3;
                const int Y = y0 + p / 18, X = x0 + p % 18;
                gload_lds16(&hT[(((size_t)b * 130 + Y) * 130 + X) * 64 + c4 * 32 + s * 8],
                            &in_s[(size_t)cbase * 8]);
            }
        }
        const unsigned short* wsrc = &w2p[(size_t)c4 * 1152 * 8];
#pragma unroll
        for (int it = 0; it < 5; it++) {
            const int cbase = it * 256 + wid * 64;
            if (cbase < 1152)
                gload_lds16(&wsrc[(size_t)(cbase + lane) * 8], &w_s[(size_t)cbase * 8]);
        }
        __syncthreads();

#pragma unroll
        for (int tap = 0; tap < 9; tap++) {
            const int dy = tap / 3, dx = tap % 3;
            short8 a[4];
#pragma unroll
            for (int mt = 0; mt < 4; mt++)
                a[mt] = *(const short8*)&in_s[(((wid * 4 + mt + dy) * 18 + ln + dx) * 4 + q) * 8];
#pragma unroll
            for (int nt = 0; nt < 2; nt++) {
                short8 bf = *(const short8*)&w_s[((tap * 32 + nt * 16 + ln) * 4 + q) * 8];
#pragma unroll
                for (int mt = 0; mt < 4; mt++)
                    acc[mt][nt] = __builtin_amdgcn_mfma_f32_16x16x32_bf16(a[mt], bf, acc[mt][nt], 0, 0, 0);
            }
        }
        __syncthreads();
    }

#pragma unroll
    for (int nt = 0; nt < 2; nt++) {
        int co = nt * 16 + ln;
        if (co < 18) {
            float bs = b2[co];
            int gch = co / 9, k = co % 9;
            int iw = k / 3, jy = k % 3;
#pragma unroll
            for (int mt = 0; mt < 4; mt++) {
                int gy = y0 + wid * 4 + mt;
#pragma unroll
                for (int r = 0; r < 4; r++) {
                    int px = q * 4 + r;
                    cond[((((size_t)b * 2 + gch) * 128 + gy) * 128 + (x0 + px)) * 12 + jy * 4 + iw]
                        = acc[mt][nt][r] + bs;
                }
            }
        }
    }
}

// ---------------------------------------------------------------------------
// apply v4 (R5-verified): direct per-output-row gather with ALIGNED +/-4px tap
// loads, no shuffles, no LDS. XCD-chunked flat grid 4096.
// ---------------------------------------------------------------------------
__global__ __launch_bounds__(256) void apply_kernel(
    const float* __restrict__ img, const float* __restrict__ cond,
    float* __restrict__ out)
{
    const int hwid = blockIdx.x;
    const int lid = (hwid & 7) * 512 + (hwid >> 3);
    const int bx = lid & 1, by = (lid >> 1) & 127, bz = lid >> 8;

    const int tid = threadIdx.x;
    const int xl = tid & 63, s = tid >> 6;
    const int x4 = bx * 64 + xl;
    const int o = by * 4 + s;                 // output row (wave-uniform)
    const int b = bz >> 1, g = bz & 1;
    const int xo = x4 * 4;

    const float* cw = &cond[((((size_t)b * 2 + g) * 128 + by) * 128 + x4) * 12];
    float4 w0 = *(const float4*)&cw[0];
    float4 w1 = *(const float4*)&cw[4];
    float4 w2 = *(const float4*)&cw[8];

    float4 C[3][3], L[3][3], R[3][3];
    const bool lok = (x4 > 0), rok_x = (x4 < 127);
#pragma unroll
    for (int jy = 0; jy < 3; jy++) {
        const int r = o - 4 + 4 * jy;
        const bool rk = (r >= 0) && (r < 512); // wave-uniform
#pragma unroll
        for (int cc = 0; cc < 3; cc++) {
            C[jy][cc] = make_float4(0.f, 0.f, 0.f, 0.f);
            L[jy][cc] = make_float4(0.f, 0.f, 0.f, 0.f);
            R[jy][cc] = make_float4(0.f, 0.f, 0.f, 0.f);
            if (rk) {
                const float* rp = &img[((((size_t)b * 6 + g * 3 + cc) * 512) + r) * 512];
                C[jy][cc] = *(const float4*)&rp[xo];
                if (lok)   L[jy][cc] = *(const float4*)&rp[xo - 4];
                if (rok_x) R[jy][cc] = *(const float4*)&rp[xo + 4];
            }
        }
    }

    float4 acc[3];
#pragma unroll
    for (int cc = 0; cc < 3; cc++) acc[cc] = make_float4(0.f, 0.f, 0.f, 0.f);

#pragma unroll
    for (int jy = 0; jy < 3; jy++) {
        const float4 wj = (jy == 0) ? w0 : (jy == 1) ? w1 : w2;
#pragma unroll
        for (int cc = 0; cc < 3; cc++) {
            const float4 l = L[jy][cc], c = C[jy][cc], r = R[jy][cc];
            acc[cc].x += l.x * wj.x + c.x * wj.y + r.x * wj.z;
            acc[cc].y += l.y * wj.x + c.y * wj.y + r.y * wj.z;
            acc[cc].z += l.z * wj.x + c.z * wj.y + r.z * wj.z;
            acc[cc].w += l.w * wj.x + c.w * wj.y + r.w * wj.z;
        }
    }

#pragma unroll
    for (int cc = 0; cc < 3; cc++)
        *(float4*)&out[((((size_t)b * 6 + g * 3 + cc) * 512) + o) * 512 + xo] = acc[cc];
}

// ---------------------------------------------------------------------------
extern "C" void kernel_launch(void* const* d_in, const int* in_sizes, int n_in,
                              void* d_out, int out_size, void* d_ws, size_t ws_size,
                              hipStream_t stream)
{
    const float* img   = (const float*)d_in[0];
    const float* ctrl  = (const float*)d_in[1];
    const float* w1    = (const float*)d_in[2];
    const float* b1    = (const float*)d_in[3];
    const float* gamma = (const float*)d_in[4];
    const float* beta  = (const float*)d_in[5];
    const float* mean  = (const float*)d_in[6];
    const float* var   = (const float*)d_in[7];
    const float* w2    = (const float*)d_in[8];
    const float* b2    = (const float*)d_in[9];
    float* out = (float*)d_out;

    char* ws = (char*)d_ws;
    unsigned short* ctrlT = (unsigned short*)ws;                        // 34,611,200 B (8*130*130*128*2)
    unsigned short* hbuf  = (unsigned short*)(ws + 34611200);           // 17,305,600 B (8*130*130*64*2)
    float*          cond  = (float*)(ws + 51916800);                    // 12,582,912 B
    unsigned short* w1p   = (unsigned short*)(ws + 64499712);           //    147,456 B
    unsigned short* w2p   = (unsigned short*)(ws + 64647168);           //     36,864 B

    transpose_kernel<<<dim3(2, 2, 1024), 256, 0, stream>>>(ctrl, ctrlT);
    prep_w_kernel<<<747, 256, 0, stream>>>(w1, w2, w1p, w2p, ctrlT, hbuf);
    conv1_mfma<<<dim3(8, 8, 8), 256, 0, stream>>>(ctrlT, w1p, b1, gamma, beta, mean, var, hbuf);
    conv2_mfma<<<dim3(8, 8, 8), 256, 0, stream>>>(hbuf, w2p, b2, cond);
    apply_kernel<<<4096, 256, 0, stream>>>(img, cond, out);
}

// Round 7
// 224.729 us; speedup vs baseline: 1.0840x; 1.0053x over previous
//
#include <hip/hip_runtime.h>

typedef __attribute__((ext_vector_type(8))) short short8;
typedef __attribute__((ext_vector_type(4))) float floatx4;

__device__ __forceinline__ unsigned short f2bf(float f) {
    union { float f; unsigned int u; } v; v.f = f;
    unsigned int r = (v.u + 0x7fffu + ((v.u >> 16) & 1u)) >> 16;
    return (unsigned short)r;
}

// async global -> LDS, 16B per lane. LDS dest = wave-uniform base + lane*16.
__device__ __forceinline__ void gload_lds16(const void* g, void* l) {
    __builtin_amdgcn_global_load_lds(
        (const __attribute__((address_space(1))) unsigned int*)g,
        (__attribute__((address_space(3))) unsigned int*)l, 16, 0, 0);
}

// ---------------------------------------------------------------------------
// W-prep + hbuf halo zeroing.
//   w1 -> [c4=4][tap=9][co=64][ci=32] bf16 ; w2 -> [c4=2][tap=9][co=32][ci=32]
//   + zero hbuf halo border (8 x 516 px x 8 uint4)
// grid 489 * 256 = 125,184 items exactly (73728 + 18432 + 33024).
// ---------------------------------------------------------------------------
__global__ __launch_bounds__(256) void prep_w_kernel(
    const float* __restrict__ w1, const float* __restrict__ w2,
    unsigned short* __restrict__ w1p, unsigned short* __restrict__ w2p,
    unsigned short* __restrict__ hbuf)
{
    int i = blockIdx.x * 256 + threadIdx.x;
    if (i < 73728) {
        int ci = i & 31; int t2 = i >> 5; int co = t2 & 63; int t3 = t2 >> 6;
        int tap = t3 % 9; int c4 = t3 / 9;
        float v = 0.f;
        if (co < 50) v = w1[((size_t)co * 128 + c4 * 32 + ci) * 9 + tap];
        w1p[i] = f2bf(v);
    } else if (i < 92160) {
        int j = i - 73728;
        int ci = j & 31; int t2 = j >> 5; int co = t2 & 31; int t3 = t2 >> 5;
        int tap = t3 % 9; int c4 = t3 / 9;
        int cig = c4 * 32 + ci;
        float v = 0.f;
        if (co < 18 && cig < 50) v = w2[((size_t)co * 50 + cig) * 9 + tap];
        w2p[j] = f2bf(v);
    } else {
        int k = i - 92160;                       // hbuf border
        int b = k / 4128, r = k % 4128;
        int px = r >> 3, u4 = r & 7;
        int Y, X;
        if (px < 130)      { Y = 0;        X = px; }
        else if (px < 260) { Y = 129;      X = px - 130; }
        else if (px < 388) { Y = px - 259; X = 0; }
        else               { Y = px - 387; X = 129; }
        *(uint4*)&hbuf[(((size_t)b * 130 + Y) * 130 + X) * 64 + u4 * 8] = make_uint4(0, 0, 0, 0);
    }
}

// ---------------------------------------------------------------------------
// conv1 MFMA v6: FUSED transpose. Reads ctrl NCHW f32 directly; converts to
// bf16 and transpose-scatters into linear LDS [324px][32ci] (contiguous 1KB
// wave-reads for MFMA A). Borders handled by load predicates (= conv zero
// padding). Weights staged via gload_lds (R6-verified linear layout).
// LDS 20.7 + 36.9 = 57.6 KB -> 2 blocks/CU. grid (8,8,8).
// ---------------------------------------------------------------------------
__global__ __launch_bounds__(256, 2) void conv1_mfma(
    const float* __restrict__ ctrl, const unsigned short* __restrict__ w1p,
    const float* __restrict__ b1, const float* __restrict__ gamma,
    const float* __restrict__ beta, const float* __restrict__ mean,
    const float* __restrict__ var, unsigned short* __restrict__ h)
{
    __shared__ unsigned short in_s[324 * 32];   // [p = row*18+col][ci 0..31]
    __shared__ unsigned short w_s[2304 * 8];    // [tap][co][4q][8ci] linear
    const int tid = threadIdx.x;
    const int x0 = blockIdx.x * 16, y0 = blockIdx.y * 16, b = blockIdx.z;
    const int wid = tid >> 6, lane = tid & 63;
    const int ln = lane & 15, q = lane >> 4;

    floatx4 acc[4][4];
#pragma unroll
    for (int mt = 0; mt < 4; mt++)
#pragma unroll
        for (int nt = 0; nt < 4; nt++) acc[mt][nt] = (floatx4)(0.f);

    for (int c4 = 0; c4 < 4; c4++) {
        // stage weights: 2304 uint4, pure linear async DMA
        const unsigned short* wsrc = &w1p[(size_t)c4 * 2304 * 8];
#pragma unroll
        for (int it = 0; it < 9; it++) {
            const int cbase = it * 256 + wid * 64;
            gload_lds16(&wsrc[(size_t)(cbase + lane) * 8], &w_s[(size_t)cbase * 8]);
        }
        // stage input: fused transpose. 576 items = 18 rows x 32 ci.
        // item: read aligned 24-float window [x0-4, x0+20), keep [x0-1, x0+17).
#pragma unroll
        for (int r = 0; r < 3; r++) {
            const int i = r * 256 + tid;
            const bool ok = i < 576;
            const int row = i >> 5, ci = i & 31;
            const int gy = y0 - 1 + row;
            float4 wv[6];
#pragma unroll
            for (int f = 0; f < 6; f++) {
                const int xs = x0 - 4 + f * 4;
                wv[f] = make_float4(0.f, 0.f, 0.f, 0.f);
                if (ok && gy >= 0 && gy < 128 && xs >= 0 && xs < 125)
                    wv[f] = *(const float4*)&ctrl[(((size_t)b * 128 + c4 * 32 + ci) * 128 + gy) * 128 + xs];
            }
            if (ok) {
                float va[24];
#pragma unroll
                for (int f = 0; f < 6; f++) {
                    va[4 * f + 0] = wv[f].x; va[4 * f + 1] = wv[f].y;
                    va[4 * f + 2] = wv[f].z; va[4 * f + 3] = wv[f].w;
                }
                unsigned short* dst = &in_s[(row * 18) * 32 + ci];
#pragma unroll
                for (int k = 0; k < 18; k++)
                    dst[k * 32] = f2bf(va[k + 3]);
            }
        }
        __syncthreads();   // drains vmcnt (gload_lds) + lgkm (scatter writes)

#pragma unroll
        for (int tap = 0; tap < 9; tap++) {
            const int dy = tap / 3, dx = tap % 3;
            short8 a[4];
#pragma unroll
            for (int mt = 0; mt < 4; mt++)
                a[mt] = *(const short8*)&in_s[((wid * 4 + mt + dy) * 18 + ln + dx) * 32 + q * 8];
#pragma unroll
            for (int nt = 0; nt < 4; nt++) {
                short8 bf = *(const short8*)&w_s[((tap * 64 + nt * 16 + ln) * 4 + q) * 8];
#pragma unroll
                for (int mt = 0; mt < 4; mt++)
                    acc[mt][nt] = __builtin_amdgcn_mfma_f32_16x16x32_bf16(a[mt], bf, acc[mt][nt], 0, 0, 0);
            }
        }
        __syncthreads();
    }

#pragma unroll
    for (int nt = 0; nt < 4; nt++) {
        int co = nt * 16 + ln;
        bool real = co < 50;
        float sc = 0.f, mn = 0.f, bt = 0.f, bs = 0.f;
        if (real) {
            sc = gamma[co] * rsqrtf(var[co] + 1e-5f);
            mn = mean[co]; bt = beta[co]; bs = b1[co];
        }
#pragma unroll
        for (int mt = 0; mt < 4; mt++) {
            int gy = y0 + wid * 4 + mt;
#pragma unroll
            for (int r = 0; r < 4; r++) {
                int px = q * 4 + r;
                float v = 0.f;
                if (real) {
                    float tv = fmaxf(acc[mt][nt][r] + bs, 0.f);
                    v = (tv - mn) * sc + bt;
                }
                // halo'd hbuf: interior write at (gy+1, gx+1)
                h[(((size_t)b * 130 + (gy + 1)) * 130 + (x0 + px + 1)) * 64 + co] = f2bf(v);
            }
        }
    }
}

// ---------------------------------------------------------------------------
// conv2 MFMA v5 (R6-verified): m97-style staging from halo'd hbuf.
// LDS 39.9 KB -> 4 blocks/CU. Epilogue writes cond[b][g][cy][cx][12].
// ---------------------------------------------------------------------------
__global__ __launch_bounds__(256) void conv2_mfma(
    const unsigned short* __restrict__ hT, const unsigned short* __restrict__ w2p,
    const float* __restrict__ b2, float* __restrict__ cond)
{
    __shared__ unsigned short in_s[1344 * 8];
    __shared__ unsigned short w_s[1152 * 8];    // 9 taps * 32 co * 4 ci-slots
    const int tid = threadIdx.x;
    const int x0 = blockIdx.x * 16, y0 = blockIdx.y * 16, b = blockIdx.z;
    const int wid = tid >> 6, lane = tid & 63;
    const int ln = lane & 15, q = lane >> 4;

    floatx4 acc[4][2];
#pragma unroll
    for (int mt = 0; mt < 4; mt++)
#pragma unroll
        for (int nt = 0; nt < 2; nt++) acc[mt][nt] = (floatx4)(0.f);

    for (int c4 = 0; c4 < 2; c4++) {
#pragma unroll
        for (int it = 0; it < 6; it++) {
            const int cbase = it * 256 + wid * 64;
            if (cbase < 1296) {
                int j = cbase + lane; if (j > 1295) j = 1295;
                const int p = j >> 2, s = j & 3;
                const int Y = y0 + p / 18, X = x0 + p % 18;
                gload_lds16(&hT[(((size_t)b * 130 + Y) * 130 + X) * 64 + c4 * 32 + s * 8],
                            &in_s[(size_t)cbase * 8]);
            }
        }
        const unsigned short* wsrc = &w2p[(size_t)c4 * 1152 * 8];
#pragma unroll
        for (int it = 0; it < 5; it++) {
            const int cbase = it * 256 + wid * 64;
            if (cbase < 1152)
                gload_lds16(&wsrc[(size_t)(cbase + lane) * 8], &w_s[(size_t)cbase * 8]);
        }
        __syncthreads();

#pragma unroll
        for (int tap = 0; tap < 9; tap++) {
            const int dy = tap / 3, dx = tap % 3;
            short8 a[4];
#pragma unroll
            for (int mt = 0; mt < 4; mt++)
                a[mt] = *(const short8*)&in_s[(((wid * 4 + mt + dy) * 18 + ln + dx) * 4 + q) * 8];
#pragma unroll
            for (int nt = 0; nt < 2; nt++) {
                short8 bf = *(const short8*)&w_s[((tap * 32 + nt * 16 + ln) * 4 + q) * 8];
#pragma unroll
                for (int mt = 0; mt < 4; mt++)
                    acc[mt][nt] = __builtin_amdgcn_mfma_f32_16x16x32_bf16(a[mt], bf, acc[mt][nt], 0, 0, 0);
            }
        }
        __syncthreads();
    }

#pragma unroll
    for (int nt = 0; nt < 2; nt++) {
        int co = nt * 16 + ln;
        if (co < 18) {
            float bs = b2[co];
            int gch = co / 9, k = co % 9;
            int iw = k / 3, jy = k % 3;
#pragma unroll
            for (int mt = 0; mt < 4; mt++) {
                int gy = y0 + wid * 4 + mt;
#pragma unroll
                for (int r = 0; r < 4; r++) {
                    int px = q * 4 + r;
                    cond[((((size_t)b * 2 + gch) * 128 + gy) * 128 + (x0 + px)) * 12 + jy * 4 + iw]
                        = acc[mt][nt][r] + bs;
                }
            }
        }
    }
}

// ---------------------------------------------------------------------------
// apply v4 (R6-verified): direct per-output-row gather with ALIGNED +/-4px tap
// loads, no shuffles, no LDS. XCD-chunked flat grid 4096.
// ---------------------------------------------------------------------------
__global__ __launch_bounds__(256) void apply_kernel(
    const float* __restrict__ img, const float* __restrict__ cond,
    float* __restrict__ out)
{
    const int hwid = blockIdx.x;
    const int lid = (hwid & 7) * 512 + (hwid >> 3);
    const int bx = lid & 1, by = (lid >> 1) & 127, bz = lid >> 8;

    const int tid = threadIdx.x;
    const int xl = tid & 63, s = tid >> 6;
    const int x4 = bx * 64 + xl;
    const int o = by * 4 + s;                 // output row (wave-uniform)
    const int b = bz >> 1, g = bz & 1;
    const int xo = x4 * 4;

    const float* cw = &cond[((((size_t)b * 2 + g) * 128 + by) * 128 + x4) * 12];
    float4 w0 = *(const float4*)&cw[0];
    float4 w1 = *(const float4*)&cw[4];
    float4 w2 = *(const float4*)&cw[8];

    float4 C[3][3], L[3][3], R[3][3];
    const bool lok = (x4 > 0), rok_x = (x4 < 127);
#pragma unroll
    for (int jy = 0; jy < 3; jy++) {
        const int r = o - 4 + 4 * jy;
        const bool rk = (r >= 0) && (r < 512); // wave-uniform
#pragma unroll
        for (int cc = 0; cc < 3; cc++) {
            C[jy][cc] = make_float4(0.f, 0.f, 0.f, 0.f);
            L[jy][cc] = make_float4(0.f, 0.f, 0.f, 0.f);
            R[jy][cc] = make_float4(0.f, 0.f, 0.f, 0.f);
            if (rk) {
                const float* rp = &img[((((size_t)b * 6 + g * 3 + cc) * 512) + r) * 512];
                C[jy][cc] = *(const float4*)&rp[xo];
                if (lok)   L[jy][cc] = *(const float4*)&rp[xo - 4];
                if (rok_x) R[jy][cc] = *(const float4*)&rp[xo + 4];
            }
        }
    }

    float4 acc[3];
#pragma unroll
    for (int cc = 0; cc < 3; cc++) acc[cc] = make_float4(0.f, 0.f, 0.f, 0.f);

#pragma unroll
    for (int jy = 0; jy < 3; jy++) {
        const float4 wj = (jy == 0) ? w0 : (jy == 1) ? w1 : w2;
#pragma unroll
        for (int cc = 0; cc < 3; cc++) {
            const float4 l = L[jy][cc], c = C[jy][cc], r = R[jy][cc];
            acc[cc].x += l.x * wj.x + c.x * wj.y + r.x * wj.z;
            acc[cc].y += l.y * wj.x + c.y * wj.y + r.y * wj.z;
            acc[cc].z += l.z * wj.x + c.z * wj.y + r.z * wj.z;
            acc[cc].w += l.w * wj.x + c.w * wj.y + r.w * wj.z;
        }
    }

#pragma unroll
    for (int cc = 0; cc < 3; cc++)
        *(float4*)&out[((((size_t)b * 6 + g * 3 + cc) * 512) + o) * 512 + xo] = acc[cc];
}

// ---------------------------------------------------------------------------
extern "C" void kernel_launch(void* const* d_in, const int* in_sizes, int n_in,
                              void* d_out, int out_size, void* d_ws, size_t ws_size,
                              hipStream_t stream)
{
    const float* img   = (const float*)d_in[0];
    const float* ctrl  = (const float*)d_in[1];
    const float* w1    = (const float*)d_in[2];
    const float* b1    = (const float*)d_in[3];
    const float* gamma = (const float*)d_in[4];
    const float* beta  = (const float*)d_in[5];
    const float* mean  = (const float*)d_in[6];
    const float* var   = (const float*)d_in[7];
    const float* w2    = (const float*)d_in[8];
    const float* b2    = (const float*)d_in[9];
    float* out = (float*)d_out;

    char* ws = (char*)d_ws;
    unsigned short* hbuf  = (unsigned short*)ws;                        // 17,305,600 B (8*130*130*64*2)
    float*          cond  = (float*)(ws + 17305600);                    // 12,582,912 B
    unsigned short* w1p   = (unsigned short*)(ws + 29888512);           //    147,456 B
    unsigned short* w2p   = (unsigned short*)(ws + 30035968);           //     36,864 B

    prep_w_kernel<<<489, 256, 0, stream>>>(w1, w2, w1p, w2p, hbuf);
    conv1_mfma<<<dim3(8, 8, 8), 256, 0, stream>>>(ctrl, w1p, b1, gamma, beta, mean, var, hbuf);
    conv2_mfma<<<dim3(8, 8, 8), 256, 0, stream>>>(hbuf, w2p, b2, cond);
    apply_kernel<<<4096, 256, 0, stream>>>(img, cond, out);
}